// Round 2
// baseline (61.785 us; speedup 1.0000x reference)
//
#include <hip/hip_runtime.h>
#include <math.h>

#define N_ATOMS 2048

// ---------------------------------------------------------------------------
// Kernel A: pure streaming. One WAVE per batch (4 waves/block, independent —
// no barrier, no LDS). Each wave computes the 3x3 cross-correlation R = y'^T y
// plus both squared norms for its batch, reduces across the 64 lanes with
// shuffles, and lane 0 writes 11 f32 partials to ws.
// ---------------------------------------------------------------------------
__global__ __launch_bounds__(256) void rmsd_partial_kernel(
    const float* __restrict__ yp, const float* __restrict__ yy,
    float* __restrict__ part /* [B][11] */)
{
    const int wave = threadIdx.x >> 6;
    const int lane = threadIdx.x & 63;
    const int b = blockIdx.x * 4 + wave;

    const float4* A  = reinterpret_cast<const float4*>(yp + (size_t)b * (N_ATOMS * 3));
    const float4* Bv = reinterpret_cast<const float4*>(yy + (size_t)b * (N_ATOMS * 3));

    float sxx = 0.f, sxy = 0.f, sxz = 0.f;
    float syx = 0.f, syy = 0.f, syz = 0.f;
    float szx = 0.f, szy = 0.f, szz = 0.f;
    float na = 0.f, nb = 0.f;

    // 2048 atoms * 3 floats = 1536 float4 = 512 groups of 3 float4 (4 atoms).
    // 64 lanes x 8 iterations.
    #pragma unroll 2
    for (int it = 0; it < 8; ++it) {
        const int g = lane + it * 64;
        const float4 a0 = A[3 * g + 0];
        const float4 a1 = A[3 * g + 1];
        const float4 a2 = A[3 * g + 2];
        const float4 b0 = Bv[3 * g + 0];
        const float4 b1 = Bv[3 * g + 1];
        const float4 b2 = Bv[3 * g + 2];

        float px[4], py[4], pz[4], qx[4], qy[4], qz[4];
        px[0] = a0.x; py[0] = a0.y; pz[0] = a0.z;
        px[1] = a0.w; py[1] = a1.x; pz[1] = a1.y;
        px[2] = a1.z; py[2] = a1.w; pz[2] = a2.x;
        px[3] = a2.y; py[3] = a2.z; pz[3] = a2.w;
        qx[0] = b0.x; qy[0] = b0.y; qz[0] = b0.z;
        qx[1] = b0.w; qy[1] = b1.x; qz[1] = b1.y;
        qx[2] = b1.z; qy[2] = b1.w; qz[2] = b2.x;
        qx[3] = b2.y; qy[3] = b2.z; qz[3] = b2.w;

        #pragma unroll
        for (int k = 0; k < 4; ++k) {
            sxx += px[k] * qx[k]; sxy += px[k] * qy[k]; sxz += px[k] * qz[k];
            syx += py[k] * qx[k]; syy += py[k] * qy[k]; syz += py[k] * qz[k];
            szx += pz[k] * qx[k]; szy += pz[k] * qy[k]; szz += pz[k] * qz[k];
            na  += px[k] * px[k] + py[k] * py[k] + pz[k] * pz[k];
            nb  += qx[k] * qx[k] + qy[k] * qy[k] + qz[k] * qz[k];
        }
    }

    float vals[11] = {sxx, sxy, sxz, syx, syy, syz, szx, szy, szz, na, nb};
    #pragma unroll
    for (int k = 0; k < 11; ++k) {
        #pragma unroll
        for (int off = 32; off > 0; off >>= 1)
            vals[k] += __shfl_down(vals[k], off, 64);
    }

    if (lane == 0) {
        float* dst = part + (size_t)b * 11;
        #pragma unroll
        for (int k = 0; k < 11; ++k) dst[k] = vals[k];
    }
}

// ---------------------------------------------------------------------------
// Kernel B: parallel QCP Newton eigen-solve (one batch per thread-iteration,
// all threads busy) + block reduction of sd + final sqrt. Single block.
// ---------------------------------------------------------------------------
__global__ __launch_bounds__(1024) void rmsd_eigen_reduce_kernel(
    const float* __restrict__ part, int Bn, float* __restrict__ out)
{
    const int t = threadIdx.x;
    double acc = 0.0;

    for (int b = t; b < Bn; b += 1024) {
        const float* S = part + (size_t)b * 11;
        const double Sxx = S[0], Sxy = S[1], Sxz = S[2];
        const double Syx = S[3], Syy = S[4], Syz = S[5];
        const double Szx = S[6], Szy = S[7], Szz = S[8];
        const double sqn = (double)S[9] + (double)S[10];

        const double Sxx2 = Sxx * Sxx, Syy2 = Syy * Syy, Szz2 = Szz * Szz;
        const double Sxy2 = Sxy * Sxy, Syz2 = Syz * Syz, Sxz2 = Sxz * Sxz;
        const double Syx2 = Syx * Syx, Szy2 = Szy * Szy, Szx2 = Szx * Szx;

        const double SyzSzymSyySzz2 = 2.0 * (Syz * Szy - Syy * Szz);
        const double Sxx2Syy2Szz2Syz2Szy2 = Syy2 + Szz2 - Sxx2 + Syz2 + Szy2;

        const double C2 = -2.0 * (Sxx2 + Syy2 + Szz2 + Sxy2 + Syx2 + Sxz2 + Szx2 + Syz2 + Szy2);
        const double C1 = 8.0 * (Sxx * Syz * Szy + Syy * Szx * Sxz + Szz * Sxy * Syx -
                                 Sxx * Syy * Szz - Syz * Szx * Sxy - Szy * Syx * Sxz);

        const double SxzpSzx = Sxz + Szx;
        const double SyzpSzy = Syz + Szy;
        const double SxypSyx = Sxy + Syx;
        const double SyzmSzy = Syz - Szy;
        const double SxzmSzx = Sxz - Szx;
        const double SxymSyx = Sxy - Syx;
        const double SxxpSyy = Sxx + Syy;
        const double SxxmSyy = Sxx - Syy;
        const double Sxy2Sxz2Syx2Szx2 = Sxy2 + Sxz2 - Syx2 - Szx2;

        const double C0 =
            Sxy2Sxz2Syx2Szx2 * Sxy2Sxz2Syx2Szx2
            + (Sxx2Syy2Szz2Syz2Szy2 + SyzSzymSyySzz2) * (Sxx2Syy2Szz2Syz2Szy2 - SyzSzymSyySzz2)
            + (-(SxzpSzx) * (SyzmSzy) + (SxymSyx) * (SxxmSyy - Szz)) *
              (-(SxzmSzx) * (SyzpSzy) + (SxymSyx) * (SxxmSyy + Szz))
            + (-(SxzpSzx) * (SyzpSzy) - (SxypSyx) * (SxxpSyy - Szz)) *
              (-(SxzmSzx) * (SyzmSzy) - (SxypSyx) * (SxxpSyy + Szz))
            + (+(SxypSyx) * (SyzpSzy) + (SxzpSzx) * (SxxmSyy + Szz)) *
              (-(SxymSyx) * (SyzmSzy) + (SxzpSzx) * (SxxpSyy + Szz))
            + (+(SxypSyx) * (SyzmSzy) + (SxzmSzx) * (SxxmSyy - Szz)) *
              (-(SxymSyx) * (SyzpSzy) + (SxzmSzx) * (SxxpSyy - Szz));

        double lam = 0.5 * sqn;
        for (int i = 0; i < 100; ++i) {
            const double old = lam;
            const double x2 = lam * lam;
            const double bp = (x2 + C2) * lam;
            const double ap = bp + C1;
            const double den = 2.0 * x2 * lam + bp + ap;
            if (den == 0.0) break;
            lam -= (ap * lam + C0) / den;
            if (fabs(lam - old) < fabs(1e-13 * lam)) break;
        }
        acc += sqn - 2.0 * lam;
    }

    #pragma unroll
    for (int off = 32; off > 0; off >>= 1)
        acc += __shfl_down(acc, off, 64);

    __shared__ double red[16];
    if ((t & 63) == 0) red[t >> 6] = acc;
    __syncthreads();

    if (t == 0) {
        double tot = 0.0;
        #pragma unroll
        for (int i = 0; i < 16; ++i) tot += red[i];
        out[0] = (float)sqrt(tot / (double)N_ATOMS);
    }
}

extern "C" void kernel_launch(void* const* d_in, const int* in_sizes, int n_in,
                              void* d_out, int out_size, void* d_ws, size_t ws_size,
                              hipStream_t stream) {
    const float* yp = (const float*)d_in[0];
    const float* yy = (const float*)d_in[1];
    float* out = (float*)d_out;
    const int B = in_sizes[0] / (N_ATOMS * 3);   // 4096

    float* part = (float*)d_ws;                  // B*11 floats = 180 KB scratch

    rmsd_partial_kernel<<<B / 4, 256, 0, stream>>>(yp, yy, part);
    rmsd_eigen_reduce_kernel<<<1, 1024, 0, stream>>>(part, B, out);
}

// Round 3
// 42.140 us; speedup vs baseline: 1.4662x; 1.4662x over previous
//
#include <hip/hip_runtime.h>
#include <math.h>

#define N_ATOMS 2048
#define FLTS_PER_BATCH (N_ATOMS * 3)   // 6144 floats = 1536 float4 = 512 groups

// ---------------------------------------------------------------------------
// Kernel A: pure streaming, maximum memory-level parallelism.
// One wave per QUARTER batch (16384 waves). Each lane: 2 groups x 3 float4
// per input = 12 independent loads, fully unrolled (all in flight before the
// FMA chain). No LDS, no barriers. Wave shuffle-reduce of 11 f32 partials,
// lane 0 writes part[b*4+q][11].
// ---------------------------------------------------------------------------
__global__ __launch_bounds__(256) void rmsd_partial_kernel(
    const float* __restrict__ yp, const float* __restrict__ yy,
    float* __restrict__ part /* [B*4][11] */)
{
    const int wid  = (blockIdx.x << 2) + (threadIdx.x >> 6);  // global wave id
    const int lane = threadIdx.x & 63;
    const int b    = wid >> 2;        // batch
    const int q    = wid & 3;         // quarter

    const float4* A  = reinterpret_cast<const float4*>(yp + (size_t)b * FLTS_PER_BATCH);
    const float4* Bv = reinterpret_cast<const float4*>(yy + (size_t)b * FLTS_PER_BATCH);

    // group g covers atoms 4g..4g+3 via float4 indices 3g,3g+1,3g+2
    float4 av[6], bv[6];
    #pragma unroll
    for (int c = 0; c < 2; ++c) {
        const int g = q * 128 + c * 64 + lane;
        av[3 * c + 0] = A[3 * g + 0];
        av[3 * c + 1] = A[3 * g + 1];
        av[3 * c + 2] = A[3 * g + 2];
        bv[3 * c + 0] = Bv[3 * g + 0];
        bv[3 * c + 1] = Bv[3 * g + 1];
        bv[3 * c + 2] = Bv[3 * g + 2];
    }

    float sxx = 0.f, sxy = 0.f, sxz = 0.f;
    float syx = 0.f, syy = 0.f, syz = 0.f;
    float szx = 0.f, szy = 0.f, szz = 0.f;
    float na = 0.f, nb = 0.f;

    #pragma unroll
    for (int c = 0; c < 2; ++c) {
        const float4 a0 = av[3 * c + 0], a1 = av[3 * c + 1], a2 = av[3 * c + 2];
        const float4 b0 = bv[3 * c + 0], b1 = bv[3 * c + 1], b2 = bv[3 * c + 2];
        float px[4], py[4], pz[4], qx[4], qy[4], qz[4];
        px[0] = a0.x; py[0] = a0.y; pz[0] = a0.z;
        px[1] = a0.w; py[1] = a1.x; pz[1] = a1.y;
        px[2] = a1.z; py[2] = a1.w; pz[2] = a2.x;
        px[3] = a2.y; py[3] = a2.z; pz[3] = a2.w;
        qx[0] = b0.x; qy[0] = b0.y; qz[0] = b0.z;
        qx[1] = b0.w; qy[1] = b1.x; qz[1] = b1.y;
        qx[2] = b1.z; qy[2] = b1.w; qz[2] = b2.x;
        qx[3] = b2.y; qy[3] = b2.z; qz[3] = b2.w;

        #pragma unroll
        for (int k = 0; k < 4; ++k) {
            sxx += px[k] * qx[k]; sxy += px[k] * qy[k]; sxz += px[k] * qz[k];
            syx += py[k] * qx[k]; syy += py[k] * qy[k]; syz += py[k] * qz[k];
            szx += pz[k] * qx[k]; szy += pz[k] * qy[k]; szz += pz[k] * qz[k];
            na  += px[k] * px[k] + py[k] * py[k] + pz[k] * pz[k];
            nb  += qx[k] * qx[k] + qy[k] * qy[k] + qz[k] * qz[k];
        }
    }

    float vals[11] = {sxx, sxy, sxz, syx, syy, syz, szx, szy, szz, na, nb};
    #pragma unroll
    for (int k = 0; k < 11; ++k) {
        #pragma unroll
        for (int off = 32; off > 0; off >>= 1)
            vals[k] += __shfl_down(vals[k], off, 64);
    }

    if (lane == 0) {
        float* dst = part + (size_t)wid * 11;
        #pragma unroll
        for (int k = 0; k < 11; ++k) dst[k] = vals[k];
    }
}

// ---------------------------------------------------------------------------
// Kernel B: one batch per THREAD (4096 threads across 16 blocks — all Newton
// solves in parallel). Combines 4 quarter-partials in f64, solves QCP quartic,
// block-reduces sd, writes one double per block.
// ---------------------------------------------------------------------------
__global__ __launch_bounds__(256) void rmsd_eigen_kernel(
    const float* __restrict__ part, double* __restrict__ blocksum)
{
    const int b = blockIdx.x * 256 + threadIdx.x;   // batch index
    const float* P = part + (size_t)b * 44;

    double S[11];
    #pragma unroll
    for (int k = 0; k < 11; ++k)
        S[k] = (double)P[k] + (double)P[11 + k] + (double)P[22 + k] + (double)P[33 + k];

    const double Sxx = S[0], Sxy = S[1], Sxz = S[2];
    const double Syx = S[3], Syy = S[4], Syz = S[5];
    const double Szx = S[6], Szy = S[7], Szz = S[8];
    const double sqn = S[9] + S[10];

    const double Sxx2 = Sxx * Sxx, Syy2 = Syy * Syy, Szz2 = Szz * Szz;
    const double Sxy2 = Sxy * Sxy, Syz2 = Syz * Syz, Sxz2 = Sxz * Sxz;
    const double Syx2 = Syx * Syx, Szy2 = Szy * Szy, Szx2 = Szx * Szx;

    const double SyzSzymSyySzz2 = 2.0 * (Syz * Szy - Syy * Szz);
    const double Sxx2Syy2Szz2Syz2Szy2 = Syy2 + Szz2 - Sxx2 + Syz2 + Szy2;

    const double C2 = -2.0 * (Sxx2 + Syy2 + Szz2 + Sxy2 + Syx2 + Sxz2 + Szx2 + Syz2 + Szy2);
    const double C1 = 8.0 * (Sxx * Syz * Szy + Syy * Szx * Sxz + Szz * Sxy * Syx -
                             Sxx * Syy * Szz - Syz * Szx * Sxy - Szy * Syx * Sxz);

    const double SxzpSzx = Sxz + Szx;
    const double SyzpSzy = Syz + Szy;
    const double SxypSyx = Sxy + Syx;
    const double SyzmSzy = Syz - Szy;
    const double SxzmSzx = Sxz - Szx;
    const double SxymSyx = Sxy - Syx;
    const double SxxpSyy = Sxx + Syy;
    const double SxxmSyy = Sxx - Syy;
    const double Sxy2Sxz2Syx2Szx2 = Sxy2 + Sxz2 - Syx2 - Szx2;

    const double C0 =
        Sxy2Sxz2Syx2Szx2 * Sxy2Sxz2Syx2Szx2
        + (Sxx2Syy2Szz2Syz2Szy2 + SyzSzymSyySzz2) * (Sxx2Syy2Szz2Syz2Szy2 - SyzSzymSyySzz2)
        + (-(SxzpSzx) * (SyzmSzy) + (SxymSyx) * (SxxmSyy - Szz)) *
          (-(SxzmSzx) * (SyzpSzy) + (SxymSyx) * (SxxmSyy + Szz))
        + (-(SxzpSzx) * (SyzpSzy) - (SxypSyx) * (SxxpSyy - Szz)) *
          (-(SxzmSzx) * (SyzmSzy) - (SxypSyx) * (SxxpSyy + Szz))
        + (+(SxypSyx) * (SyzpSzy) + (SxzpSzx) * (SxxmSyy + Szz)) *
          (-(SxymSyx) * (SyzmSzy) + (SxzpSzx) * (SxxpSyy + Szz))
        + (+(SxypSyx) * (SyzmSzy) + (SxzmSzx) * (SxxmSyy - Szz)) *
          (-(SxymSyx) * (SyzpSzy) + (SxzmSzx) * (SxxpSyy - Szz));

    double lam = 0.5 * sqn;
    for (int i = 0; i < 100; ++i) {
        const double old = lam;
        const double x2 = lam * lam;
        const double bp = (x2 + C2) * lam;
        const double ap = bp + C1;
        const double den = 2.0 * x2 * lam + bp + ap;
        if (den == 0.0) break;
        lam -= (ap * lam + C0) / den;
        if (fabs(lam - old) < fabs(1e-13 * lam)) break;
    }
    double sd = sqn - 2.0 * lam;

    // block reduction (deterministic tree)
    #pragma unroll
    for (int off = 32; off > 0; off >>= 1)
        sd += __shfl_down(sd, off, 64);

    __shared__ double red[4];
    const int t = threadIdx.x;
    if ((t & 63) == 0) red[t >> 6] = sd;
    __syncthreads();
    if (t == 0)
        blocksum[blockIdx.x] = red[0] + red[1] + red[2] + red[3];
}

// ---------------------------------------------------------------------------
// Kernel C: reduce 16 block sums, final sqrt.
// ---------------------------------------------------------------------------
__global__ __launch_bounds__(64) void rmsd_final_kernel(
    const double* __restrict__ blocksum, int nblk, float* __restrict__ out)
{
    if (threadIdx.x == 0) {
        double tot = 0.0;
        for (int i = 0; i < nblk; ++i) tot += blocksum[i];
        out[0] = (float)sqrt(tot / (double)N_ATOMS);
    }
}

extern "C" void kernel_launch(void* const* d_in, const int* in_sizes, int n_in,
                              void* d_out, int out_size, void* d_ws, size_t ws_size,
                              hipStream_t stream) {
    const float* yp = (const float*)d_in[0];
    const float* yy = (const float*)d_in[1];
    float* out = (float*)d_out;
    const int B = in_sizes[0] / FLTS_PER_BATCH;   // 4096

    float*  part     = (float*)d_ws;                          // B*44 floats = 720 KB
    double* blocksum = (double*)((char*)d_ws + (size_t)B * 44 * sizeof(float));

    const int nblkB = B / 256;                                // 16
    rmsd_partial_kernel<<<B, 256, 0, stream>>>(yp, yy, part);
    rmsd_eigen_kernel<<<nblkB, 256, 0, stream>>>(part, blocksum);
    rmsd_final_kernel<<<1, 64, 0, stream>>>(blocksum, nblkB, out);
}